// Round 1
// baseline (484.601 us; speedup 1.0000x reference)
//
#include <hip/hip_runtime.h>

#define Bsz 4096
#define Tt  256
#define Ff  32
#define H1  64
#define H2  32
#define NTAPS 3
#define BT  16
#define NTHR 512

typedef _Float16 half8  __attribute__((ext_vector_type(8)));
typedef _Float16 half2v __attribute__((ext_vector_type(2)));
typedef float    f32x4  __attribute__((ext_vector_type(4)));

#define H1S 72   // sH1 row stride (f16), 144B = 16B-aligned rows
#define XS  40
#define H2S 40
#define GSR 20   // sG row stride (f32): [tile][col][row pad 20] keeps b128 16B-aligned
#define HDS 33

__device__ __forceinline__ float fast_sigmoid(float x) {
    float e = __builtin_amdgcn_exp2f(-1.4426950408889634f * x);
    return __builtin_amdgcn_rcpf(1.0f + e);
}
__device__ __forceinline__ float fast_tanh(float x) {
    float ax = __builtin_fabsf(x);
    float e = __builtin_amdgcn_exp2f(-2.8853900817779268f * ax);  // exp(-2|x|)
    float t = 1.0f - 2.0f * e * __builtin_amdgcn_rcpf(1.0f + e);
    return __builtin_copysignf(t, x);
}

#define MFMA16(a, b, c) __builtin_amdgcn_mfma_f32_16x16x32_f16((a), (b), (c), 0, 0, 0)

__global__ __launch_bounds__(NTHR, 1)
void lstm2_fused(const float* __restrict__ x,
                 const float* __restrict__ Wih1, const float* __restrict__ Whh1,
                 const float* __restrict__ bih1, const float* __restrict__ bhh1,
                 const float* __restrict__ Wih2, const float* __restrict__ Whh2,
                 const float* __restrict__ bih2, const float* __restrict__ bhh2,
                 const float* __restrict__ Whead, const float* __restrict__ bhead,
                 float* __restrict__ out)
{
    // h1(t) lives in sH1[t&1]; h2(t) in sH2[t&1]; x(t) in sX[t&1]
    __shared__ __align__(16) _Float16 sH1[2][BT][H1S];
    __shared__ __align__(16) _Float16 sX [2][BT][XS];
    __shared__ __align__(16) _Float16 sH2[2][BT][H2S];
    __shared__ __align__(16) float    sG [24][16][GSR];   // gate preacts [tile][col][row]
    __shared__ __align__(16) float    sHead[BT][HDS];

    const int tid  = threadIdx.x;
    const int wid  = tid >> 6;       // 0..7
    const int lane = tid & 63;
    const int l15  = lane & 15;
    const int q    = lane >> 4;      // 0..3
    const int b0   = blockIdx.x * BT;

    // ---- weight fragments into registers (one time) ----
    // wave w owns tiles {w (L1), w+8 (L1), 16+w (L2)}; B-frag: lane -> W[g = tile*16 + l15][k = c*32 + q*8 + e]
    half8 wA[3], wB[3], wC[3];
    f32x4 bias0, bias1, bias2;
    {
        int gA = wid * 16 + l15;           // L1 gate row, tile wid
        int gB = (wid + 8) * 16 + l15;     // L1 gate row, tile wid+8
        int gC = wid * 16 + l15;           // L2 gate row, tile 16+wid
        #pragma unroll
        for (int c = 0; c < 3; ++c) {
            half8 va, vb, vc;
            #pragma unroll
            for (int e = 0; e < 8; ++e) {
                int k = c * 32 + q * 8 + e;
                float fa = (k < H1) ? Whh1[gA * H1 + k] : Wih1[gA * Ff + (k - H1)];
                float fb = (k < H1) ? Whh1[gB * H1 + k] : Wih1[gB * Ff + (k - H1)];
                float fc = (k < H2) ? Whh2[gC * H2 + k] : Wih2[gC * H1 + (k - H2)];
                va[e] = (_Float16)fa; vb[e] = (_Float16)fb; vc[e] = (_Float16)fc;
            }
            wA[c] = va; wB[c] = vb; wC[c] = vc;
        }
        float v0 = bih1[gA] + bhh1[gA];
        float v1 = bih1[gB] + bhh1[gB];
        float v2 = bih2[gC] + bhh2[gC];
        bias0 = (f32x4){v0, v0, v0, v0};
        bias1 = (f32x4){v1, v1, v1, v1};
        bias2 = (f32x4){v2, v2, v2, v2};
    }

    // ---- zero h(-1) buffers ----
    for (int idx = tid; idx < BT * H1S; idx += NTHR) ((_Float16*)sH1[1])[idx] = (_Float16)0.0f;
    for (int idx = tid; idx < BT * H2S; idx += NTHR) ((_Float16*)sH2[1])[idx] = (_Float16)0.0f;

    // ---- x prologue: x(0) -> sX[0]; prefetch x(1), x(2) into regs ----
    float2 rA, rB;
    int xb = 0, xf = 0;
    if (tid < 256) {
        xb = tid >> 4; xf = (tid & 15) * 2;
        const float* xp = x + ((size_t)(b0 + xb) * Tt + 0) * Ff + xf;
        float2 v0 = *(const float2*)xp;
        half2v h0; h0[0] = (_Float16)v0.x; h0[1] = (_Float16)v0.y;
        *(half2v*)&sX[0][xb][xf] = h0;
        rA = *(const float2*)(xp + 1 * Ff);
        rB = *(const float2*)(xp + 2 * Ff);
    }
    __syncthreads();

    // per-thread activation units: L1 A (b=tid>>6, h=tid&63), L1 B (b=8+(tid>>6)), L2 (b=tid>>5, h=tid&31)
    float c1a = 0.0f, c1b = 0.0f, c2s = 0.0f;
    const int uaB = tid >> 6, uaH = tid & 63;
    const int ucB = tid >> 5, ucH = tid & 31;

    for (int i = 0; i <= Tt; ++i) {
        const int cur = i & 1, nxt = cur ^ 1;

        // ============ MFMA phase: L1 step i, L2 step i-1 ============
        half8 a0 = *(const half8*)&sH1[nxt][l15][q * 8];        // h1(i-1) k 0..31
        half8 a1 = *(const half8*)&sH1[nxt][l15][32 + q * 8];   // h1(i-1) k 32..63
        if (i < Tt) {
            half8 ax = *(const half8*)&sX[cur][l15][q * 8];     // x(i)
            f32x4 accA = MFMA16(a0, wA[0], bias0);
            accA = MFMA16(a1, wA[1], accA);
            accA = MFMA16(ax, wA[2], accA);
            *(f32x4*)&sG[wid][l15][4 * q] = accA;
            f32x4 accB = MFMA16(a0, wB[0], bias1);
            accB = MFMA16(a1, wB[1], accB);
            accB = MFMA16(ax, wB[2], accB);
            *(f32x4*)&sG[wid + 8][l15][4 * q] = accB;
        }
        if (i >= 1) {
            half8 ah = *(const half8*)&sH2[cur][l15][q * 8];    // h2(i-2)
            f32x4 accC = MFMA16(ah, wC[0], bias2);
            accC = MFMA16(a0, wC[1], accC);
            accC = MFMA16(a1, wC[2], accC);
            *(f32x4*)&sG[16 + wid][l15][4 * q] = accC;
        }
        __syncthreads();

        // ============ activation phase ============
        if (i < Tt) {
            {   // L1 unit A
                int b = uaB, h = uaH, t0 = h >> 4, col = h & 15;
                float ig = fast_sigmoid(sG[0 + t0][col][b]);
                float fg = fast_sigmoid(sG[4 + t0][col][b]);
                float gg = fast_tanh   (sG[8 + t0][col][b]);
                float og = fast_sigmoid(sG[12 + t0][col][b]);
                c1a = fg * c1a + ig * gg;
                float hh = og * fast_tanh(c1a);
                sH1[cur][b][h] = (_Float16)hh;
            }
            {   // L1 unit B
                int b = 8 + uaB, h = uaH, t0 = h >> 4, col = h & 15;
                float ig = fast_sigmoid(sG[0 + t0][col][b]);
                float fg = fast_sigmoid(sG[4 + t0][col][b]);
                float gg = fast_tanh   (sG[8 + t0][col][b]);
                float og = fast_sigmoid(sG[12 + t0][col][b]);
                c1b = fg * c1b + ig * gg;
                float hh = og * fast_tanh(c1b);
                sH1[cur][b][h] = (_Float16)hh;
            }
        }
        if (i >= 1) {   // L2 unit, step i-1
            int b = ucB, h = ucH, t0 = h >> 4, col = h & 15;
            float ig = fast_sigmoid(sG[16 + 0 + t0][col][b]);
            float fg = fast_sigmoid(sG[16 + 2 + t0][col][b]);
            float gg = fast_tanh   (sG[16 + 4 + t0][col][b]);
            float og = fast_sigmoid(sG[16 + 6 + t0][col][b]);
            c2s = fg * c2s + ig * gg;
            float hh = og * fast_tanh(c2s);
            sH2[nxt][b][h] = (_Float16)hh;   // h2(i-1) -> sH2[(i-1)&1]
            if (i == Tt) sHead[b][h] = hh;
        }
        // ============ x prefetch duty (waves 0-3) ============
        if (tid < 256) {
            if (i + 1 < Tt) {
                half2v hx; hx[0] = (_Float16)rA.x; hx[1] = (_Float16)rA.y;
                *(half2v*)&sX[nxt][xb][xf] = hx;   // x(i+1) -> sX[(i+1)&1]
            }
            rA = rB;
            int tld = (i + 3 < Tt) ? (i + 3) : (Tt - 1);
            rB = *(const float2*)(x + ((size_t)(b0 + xb) * Tt + tld) * Ff + xf);
        }
        __syncthreads();
    }

    // ============ head: out[b,n] = b_head[n] + sum_k h2_last[b,k] * W_head[n,k] ============
    if (tid < BT * NTAPS) {
        int b = tid / NTAPS, n = tid - b * NTAPS;
        float s = bhead[n];
        #pragma unroll
        for (int k = 0; k < H2; ++k) s = fmaf(sHead[b][k], Whead[n * H2 + k], s);
        out[(size_t)(b0 + b) * NTAPS + n] = s;
    }
}

extern "C" void kernel_launch(void* const* d_in, const int* in_sizes, int n_in,
                              void* d_out, int out_size, void* d_ws, size_t ws_size,
                              hipStream_t stream) {
    const float* xp    = (const float*)d_in[0];
    const float* Wih1  = (const float*)d_in[1];
    const float* Whh1  = (const float*)d_in[2];
    const float* bih1  = (const float*)d_in[3];
    const float* bhh1  = (const float*)d_in[4];
    const float* Wih2  = (const float*)d_in[5];
    const float* Whh2  = (const float*)d_in[6];
    const float* bih2  = (const float*)d_in[7];
    const float* bhh2  = (const float*)d_in[8];
    const float* Whead = (const float*)d_in[9];
    const float* bhead = (const float*)d_in[10];
    float* outp = (float*)d_out;

    hipLaunchKernelGGL(lstm2_fused, dim3(Bsz / BT), dim3(NTHR), 0, stream,
                       xp, Wih1, Whh1, bih1, bhh1, Wih2, Whh2, bih2, bhh2,
                       Whead, bhead, outp);
}

// Round 2
// 430.664 us; speedup vs baseline: 1.1252x; 1.1252x over previous
//
#include <hip/hip_runtime.h>

#define Bsz 4096
#define Tt  256
#define Ff  32
#define H1  64
#define H2  32
#define NTAPS 3
#define BT  16
#define NTHR 768   // 12 waves: 8 L1 wave-tasks + 4 L2 wave-tasks (bundle x half)

typedef _Float16 half8  __attribute__((ext_vector_type(8)));
typedef _Float16 half2v __attribute__((ext_vector_type(2)));
typedef float    f32x4  __attribute__((ext_vector_type(4)));

#define H1S 72   // f16 row stride: 144B, 16B-aligned, even bank spread (4*(l15+q) groups)
#define XS  40   // f16 row stride: 80B, 16B-aligned
#define H2S 40
#define HDS 33

__device__ __forceinline__ float fast_sigmoid(float x) {
    float e = __builtin_amdgcn_exp2f(-1.4426950408889634f * x);
    return __builtin_amdgcn_rcpf(1.0f + e);
}
__device__ __forceinline__ float fast_tanh(float x) {
    float ax = __builtin_fabsf(x);
    float e = __builtin_amdgcn_exp2f(-2.8853900817779268f * ax);  // exp(-2|x|)
    float t = 1.0f - 2.0f * e * __builtin_amdgcn_rcpf(1.0f + e);
    return __builtin_copysignf(t, x);
}

#define MFMA16(a, b, c) __builtin_amdgcn_mfma_f32_16x16x32_f16((a), (b), (c), 0, 0, 0)

__global__ __launch_bounds__(NTHR, 3)
void lstm2_fused(const float* __restrict__ x,
                 const float* __restrict__ Wih1, const float* __restrict__ Whh1,
                 const float* __restrict__ bih1, const float* __restrict__ bhh1,
                 const float* __restrict__ Wih2, const float* __restrict__ Whh2,
                 const float* __restrict__ bih2, const float* __restrict__ bhh2,
                 const float* __restrict__ Whead, const float* __restrict__ bhead,
                 float* __restrict__ out)
{
    // h1(t) in sH1[t&1]; h2(t) in sH2[t&1]; x(t) in sX[t&1]
    __shared__ __align__(16) _Float16 sH1[2][BT][H1S];
    __shared__ __align__(16) _Float16 sX [2][BT][XS];
    __shared__ __align__(16) _Float16 sH2[2][BT][H2S];
    __shared__ __align__(16) float    sHead[BT][HDS];

    const int tid  = threadIdx.x;
    const int wid  = tid >> 6;        // 0..11
    const int lane = tid & 63;
    const int l15  = lane & 15;
    const int q    = lane >> 4;       // 0..3
    const int b0   = blockIdx.x * BT;

    const bool isL1 = (wid < 8);
    const int  hg   = isL1 ? (wid >> 1) : ((wid - 8) >> 1);  // h-group (L1: 0..3, L2: 0..1)
    const int  hf   = wid & 1;                               // row-half (acc regs 2hf, 2hf+1)
    const int  r0   = 2 * hf, r1 = r0 + 1;

    // ---- per-wave weight fragments (registers, one time) ----
    // w[G][c]: B-frag for gate G (i,f,g,o), K-chunk c. Lane -> W[gr = base + l15][k = c*32+q*8+e]
    half8 w[4][3];
    float bias[4];
    if (isL1) {
        #pragma unroll
        for (int G = 0; G < 4; ++G) {
            int gr = G * 64 + hg * 16 + l15;
            #pragma unroll
            for (int c = 0; c < 3; ++c) {
                half8 v;
                #pragma unroll
                for (int e = 0; e < 8; ++e) {
                    int k = c * 32 + q * 8 + e;                    // 0..63: h1(t-1), 64..95: x(t)
                    float f = (k < H1) ? Whh1[gr * H1 + k] : Wih1[gr * Ff + (k - H1)];
                    v[e] = (_Float16)f;
                }
                w[G][c] = v;
            }
            bias[G] = bih1[gr] + bhh1[gr];
        }
    } else {
        #pragma unroll
        for (int G = 0; G < 4; ++G) {
            int gr = G * 32 + hg * 16 + l15;
            #pragma unroll
            for (int c = 0; c < 3; ++c) {
                half8 v;
                #pragma unroll
                for (int e = 0; e < 8; ++e) {
                    int kk = q * 8 + e;                            // c0: h2(t-1), c1/c2: h1(t)
                    float f = (c == 0) ? Whh2[gr * H2 + kk]
                                       : Wih2[gr * H1 + (c - 1) * 32 + kk];
                    v[e] = (_Float16)f;
                }
                w[G][c] = v;
            }
            bias[G] = bih2[gr] + bhh2[gr];
        }
    }

    // ---- zero h(-1) buffers (buf 1 is read at the first use) ----
    for (int idx = tid; idx < BT * H1S; idx += NTHR) ((_Float16*)sH1[1])[idx] = (_Float16)0.0f;
    for (int idx = tid; idx < BT * H2S; idx += NTHR) ((_Float16*)sH2[1])[idx] = (_Float16)0.0f;

    // ---- x prologue (L2 waves own x duty): x(0)->sX[0]; prefetch x(1),x(2) ----
    float2 rA, rB;
    int xb = 0, xf = 0;
    if (tid >= 512) {
        int t = tid - 512;                 // 0..255
        xb = t >> 4; xf = (t & 15) * 2;
        const float* xp = x + ((size_t)(b0 + xb) * Tt) * Ff + xf;
        float2 v0 = *(const float2*)xp;
        half2v h0; h0[0] = (_Float16)v0.x; h0[1] = (_Float16)v0.y;
        *(half2v*)&sX[0][xb][xf] = h0;
        rA = *(const float2*)(xp + 1 * Ff);
        rB = *(const float2*)(xp + 2 * Ff);
    }
    __syncthreads();

    float cs0 = 0.0f, cs1 = 0.0f;   // cell state for this lane's 2 units

    for (int i = 0; i <= Tt; ++i) {
        const int cur = i & 1, nxt = cur ^ 1;
        const bool active = isL1 ? (i < Tt) : (i >= 1);

        if (active) {
            // A-frags: all roles read h1(i-1); third frag is x(i) (L1) or h2(i-2) (L2)
            half8 a0 = *(const half8*)&sH1[nxt][l15][q * 8];
            half8 a1 = *(const half8*)&sH1[nxt][l15][32 + q * 8];
            half8 A0, A1, A2;
            if (isL1) {
                half8 ax = *(const half8*)&sX[cur][l15][q * 8];
                A0 = a0; A1 = a1; A2 = ax;          // K order: h1lo, h1hi, x
            } else {
                half8 ah = *(const half8*)&sH2[cur][l15][q * 8];
                A0 = ah; A1 = a0; A2 = a1;          // K order: h2, h1lo, h1hi
            }
            f32x4 acc[4];
            #pragma unroll
            for (int G = 0; G < 4; ++G) {
                f32x4 a = {bias[G], bias[G], bias[G], bias[G]};
                a = MFMA16(A0, w[G][0], a);
                a = MFMA16(A1, w[G][1], a);
                a = MFMA16(A2, w[G][2], a);
                acc[G] = a;
            }

            _Float16* hdst; int rs;
            if (isL1) { hdst = &sH1[cur][0][hg * 16 + l15]; rs = H1S; }   // h1(i) -> buf cur
            else      { hdst = &sH2[nxt][0][hg * 16 + l15]; rs = H2S; }   // h2(i-1) -> buf nxt

            {   // unit r0: (b = q*4+r0, h = hg*16+l15)
                float i_ = fast_sigmoid(acc[0][r0]);
                float f_ = fast_sigmoid(acc[1][r0]);
                float g_ = fast_tanh   (acc[2][r0]);
                float o_ = fast_sigmoid(acc[3][r0]);
                cs0 = f_ * cs0 + i_ * g_;
                float hh = o_ * fast_tanh(cs0);
                hdst[(q * 4 + r0) * rs] = (_Float16)hh;
                if (!isL1 && i == Tt) sHead[q * 4 + r0][hg * 16 + l15] = hh;
            }
            {   // unit r1
                float i_ = fast_sigmoid(acc[0][r1]);
                float f_ = fast_sigmoid(acc[1][r1]);
                float g_ = fast_tanh   (acc[2][r1]);
                float o_ = fast_sigmoid(acc[3][r1]);
                cs1 = f_ * cs1 + i_ * g_;
                float hh = o_ * fast_tanh(cs1);
                hdst[(q * 4 + r1) * rs] = (_Float16)hh;
                if (!isL1 && i == Tt) sHead[q * 4 + r1][hg * 16 + l15] = hh;
            }
        }

        // x duty (L2 waves): stage x(i+1), prefetch x(i+3)
        if (tid >= 512) {
            if (i + 1 < Tt) {
                half2v hx; hx[0] = (_Float16)rA.x; hx[1] = (_Float16)rA.y;
                *(half2v*)&sX[nxt][xb][xf] = hx;
            }
            rA = rB;
            int tld = (i + 3 < Tt) ? (i + 3) : (Tt - 1);
            rB = *(const float2*)(x + ((size_t)(b0 + xb) * Tt + tld) * Ff + xf);
        }
        __syncthreads();   // single barrier per step (double buffers carry all deps)
    }

    // ---- head: out[b,n] = b_head[n] + sum_k h2_last[b,k] * W_head[n,k] ----
    if (tid < BT * NTAPS) {
        int b = tid / NTAPS, n = tid - b * NTAPS;
        float s = bhead[n];
        #pragma unroll
        for (int k = 0; k < H2; ++k) s = fmaf(sHead[b][k], Whead[n * H2 + k], s);
        out[(size_t)(b0 + b) * NTAPS + n] = s;
    }
}

extern "C" void kernel_launch(void* const* d_in, const int* in_sizes, int n_in,
                              void* d_out, int out_size, void* d_ws, size_t ws_size,
                              hipStream_t stream) {
    const float* xp    = (const float*)d_in[0];
    const float* Wih1  = (const float*)d_in[1];
    const float* Whh1  = (const float*)d_in[2];
    const float* bih1  = (const float*)d_in[3];
    const float* bhh1  = (const float*)d_in[4];
    const float* Wih2  = (const float*)d_in[5];
    const float* Whh2  = (const float*)d_in[6];
    const float* bih2  = (const float*)d_in[7];
    const float* bhh2  = (const float*)d_in[8];
    const float* Whead = (const float*)d_in[9];
    const float* bhead = (const float*)d_in[10];
    float* outp = (float*)d_out;

    hipLaunchKernelGGL(lstm2_fused, dim3(Bsz / BT), dim3(NTHR), 0, stream,
                       xp, Wih1, Whh1, bih1, bhh1, Wih2, Whh2, bih2, bhh2,
                       Whead, bhead, outp);
}